// Round 5
// baseline (427.464 us; speedup 1.0000x reference)
//
#include <hip/hip_runtime.h>

// LSTM: B=1024, S=512, E=H=50, fp32 in/out.
// Grid: 512 blocks x 256 threads (4 waves). Each block owns 2 batch chains for all 512 steps
// -> 2 blocks/CU co-resident (2 waves/SIMD) so independent recurrences hide each other's
//    serial latency (barrier + LDS round-trip + MFMA + transcendental chain).
// gates(16x16 tiles) = W_reordered(208x128, fp16 in VGPRs) @ [x;h] (128x16, fp16 in LDS).
// Gate reorder j = h*4 + g  ->  each lane's 4 acc regs are {i,f,g,o} for one (chain,h): lane-local cell update.
// K layout: k 0-49 = x, 50-63 = 0-pad, 64-113 = h, 114-127 = 0-pad.
// Software pipeline: x-part of step t+1 computed during step t, off the h-recurrence critical path.

typedef __attribute__((ext_vector_type(8))) _Float16 f16x8;  // 8 x fp16 (4 VGPRs) MFMA operand
typedef __attribute__((ext_vector_type(4))) float f32x4;

__device__ __forceinline__ float fast_sigmoid(float z) {
  return __builtin_amdgcn_rcpf(1.0f + __expf(-z));
}
__device__ __forceinline__ float fast_tanh(float z) {
  return 1.0f - 2.0f * __builtin_amdgcn_rcpf(1.0f + __expf(2.0f * z));
}

__global__ __launch_bounds__(256, 2) void lstm_fused(
    const float* __restrict__ xg,     // (1024, 512, 50)
    const float* __restrict__ W_ih,   // (200, 50)
    const float* __restrict__ W_hh,   // (200, 50)
    const float* __restrict__ b_ih,   // (200,)
    const float* __restrict__ b_hh,   // (200,)
    float* __restrict__ out)          // (1024, 1, 50)
{
  constexpr int S = 512, E = 50, H = 50;
  constexpr int CPB = 2;              // chains per block
  const int tid  = threadIdx.x;
  const int lane = tid & 63;
  const int wv   = tid >> 6;
  const int c0   = blockIdx.x * CPB;  // first chain of this block

  // LDS: xbuf ring[4 slots][2 kt][4 chain-slots][64B]  = 2048 B
  //      hbuf ring[2 slots][2 kt][4 chain-slots][64B]  = 1024 B  (at +2048)
  // (chain-slots 2,3 stay zero; MFMA N-cols 2-15 are benign duplicates/zeros)
  __shared__ __align__(16) unsigned char lds[3072];
  for (int i = tid; i < 3072 / 4; i += 256) reinterpret_cast<unsigned*>(lds)[i] = 0u;

  const int m  = lane & 15;   // gate-row within M-tile (A m-index), also D col for B
  const int kg = lane >> 4;   // k-group of 8 for A/B operands; D row-group
  const int tstart = (wv == 0) ? 0 : (3 * wv + 1);  // tiles {0-3},{4-6},{7-9},{10-12}
  const int tcnt   = (wv == 0) ? 4 : 3;

  // ---- W fragments: register-stationary fp16 for all 512 steps ----
  f16x8 wfr[4][4];
  f32x4 bias[4];
#pragma unroll
  for (int i = 0; i < 4; ++i) {
    const int  mt    = tstart + i;
    const bool tv    = (i < tcnt);
    const int  j     = mt * 16 + m;     // reordered gate idx = h*4 + g
    const int  hh    = j >> 2, g = j & 3;
    const bool rowok = tv && (hh < H);
#pragma unroll
    for (int kt = 0; kt < 4; ++kt) {
      f16x8 s;
#pragma unroll
      for (int jj = 0; jj < 8; ++jj) {
        const int k = kt * 32 + kg * 8 + jj;
        float w = 0.0f;
        if (rowok) {
          if (k < 50)                  w = W_ih[(g * 50 + hh) * 50 + k];
          else if (k >= 64 && k < 114) w = W_hh[(g * 50 + hh) * 50 + (k - 64)];
        }
        s[jj] = (_Float16)w;
      }
      wfr[i][kt] = s;
    }
    f32x4 bv;
#pragma unroll
    for (int r = 0; r < 4; ++r) {
      const int jr = mt * 16 + kg * 4 + r;   // D row = kg*4 + r
      const int hr = jr >> 2, gr = jr & 3;
      bv[r] = (tv && hr < H) ? (b_ih[gr * 50 + hr] + b_hh[gr * 50 + hr]) : 0.0f;
    }
    bias[i] = bv;
  }

  // ---- x prefetch mapping: threads 0..99 each own one (chain,e) ----
  const int  xc   = tid / 50;          // 0..1 for tid<100
  const int  xe   = tid - xc * 50;
  const bool xok  = (tid < CPB * 50);
  const long xbase = ((long)(c0 + xc) * S) * E + xe;
  const int  xoff  = ((xe >> 5) << 8) + (xc << 6) + ((xe & 31) << 1);

  __syncthreads();   // zeros visible (pads + h0 = 0)
  if (xok) {
    *reinterpret_cast<_Float16*>(lds + 0 * 512 + xoff) = (_Float16)xg[xbase + 0 * E];
    *reinterpret_cast<_Float16*>(lds + 1 * 512 + xoff) = (_Float16)xg[xbase + 1 * E];
  }
  float xra = 0.f, xrb = 0.f, xrc = 0.f, xrd = 0.f;   // 2-step-deep prefetch regs
  if (xok) { xra = xg[xbase + 2 * E]; xrb = xg[xbase + 3 * E]; }
  __syncthreads();

  float cst[4] = {0.f, 0.f, 0.f, 0.f};               // c state, lane-resident
  const int  bc      = lane & (CPB - 1);              // effective chain (cols CPB..15 duplicate, unused)
  const bool actlane = (m < CPB);                     // lanes holding real chains' D columns
  const unsigned bro = (unsigned)(bc << 6) + (unsigned)(kg << 4);

  // ---- prime xcur = bias + W_x @ x[0] (slot 0) ----
  f32x4 xcur[4];
  {
    const f16x8 b0 = *reinterpret_cast<const f16x8*>(lds + 0u + bro);
    const f16x8 b1 = *reinterpret_cast<const f16x8*>(lds + 256u + bro);
#pragma unroll
    for (int i = 0; i < 4; ++i) {
      f32x4 a = bias[i];
      a = __builtin_amdgcn_mfma_f32_16x16x32_f16(wfr[i][0], b0, a, 0, 0, 0);
      a = __builtin_amdgcn_mfma_f32_16x16x32_f16(wfr[i][1], b1, a, 0, 0, 0);
      xcur[i] = a;
    }
  }

  auto step = [&](int t, float& P, float& Q) {
    // issue x[t+4] early (lands ~2 steps later)
    if (xok && (t + 4) < S) Q = xg[xbase + (t + 4) * E];

    const unsigned hs = 2048u + (unsigned)(t & 1) * 512u;
    const unsigned xs = (unsigned)((t + 1) & 3) * 512u;   // x slot for step t+1
    const f16x8 b2  = *reinterpret_cast<const f16x8*>(lds + hs + bro);
    const f16x8 b3  = *reinterpret_cast<const f16x8*>(lds + hs + 256u + bro);
    const f16x8 nb0 = *reinterpret_cast<const f16x8*>(lds + xs + bro);
    const f16x8 nb1 = *reinterpret_cast<const f16x8*>(lds + xs + 256u + bro);

    // critical path: h-part, chain depth 2, C-in = precomputed x-part
    f32x4 acc[4];
#pragma unroll
    for (int i = 0; i < 4; ++i) {
      f32x4 a = xcur[i];
      a = __builtin_amdgcn_mfma_f32_16x16x32_f16(wfr[i][2], b2, a, 0, 0, 0);
      a = __builtin_amdgcn_mfma_f32_16x16x32_f16(wfr[i][3], b3, a, 0, 0, 0);
      acc[i] = a;
    }

    if (actlane) {
#pragma unroll
      for (int i = 0; i < 4; ++i) {
        const int hix = 4 * (tstart + i) + kg;
        if (i < tcnt && hix < H) {
          const float ig = fast_sigmoid(acc[i][0]);   // reg r = gate type (i,f,g,o)
          const float fg = fast_sigmoid(acc[i][1]);
          const float gg = fast_tanh   (acc[i][2]);
          const float og = fast_sigmoid(acc[i][3]);
          const float c  = fg * cst[i] + ig * gg;
          cst[i] = c;
          const float hv = og * fast_tanh(c);
          if (t == S - 1) {
            out[(long)(c0 + bc) * H + hix] = hv;      // final h, fp32
          } else {
            const int kth = hix >> 5, kl = hix & 31;
            *reinterpret_cast<_Float16*>(
                lds + 2048u + (unsigned)((t + 1) & 1) * 512u +
                (unsigned)(kth << 8) + (unsigned)(bc << 6) + (unsigned)(kl << 1)) = (_Float16)hv;
          }
        }
      }
    }

    // off-critical-path: x-part for step t+1 (x[t+1] resident since step t-1)
#pragma unroll
    for (int i = 0; i < 4; ++i) {
      f32x4 a = bias[i];
      a = __builtin_amdgcn_mfma_f32_16x16x32_f16(wfr[i][0], nb0, a, 0, 0, 0);
      a = __builtin_amdgcn_mfma_f32_16x16x32_f16(wfr[i][1], nb1, a, 0, 0, 0);
      xcur[i] = a;
    }

    // write x[t+2] (issued 2 steps ago) into its ring slot
    if (xok && (t + 2) < S) {
      *reinterpret_cast<_Float16*>(lds + (unsigned)((t + 2) & 3) * 512u + xoff) = (_Float16)P;
    }
    __syncthreads();   // slot t+1 (h and x) complete before next step reads
  };

  for (int t = 0; t < S; t += 4) {
    step(t + 0, xra, xrc);
    step(t + 1, xrb, xrd);
    step(t + 2, xrc, xra);
    step(t + 3, xrd, xrb);
  }
}

extern "C" void kernel_launch(void* const* d_in, const int* in_sizes, int n_in,
                              void* d_out, int out_size, void* d_ws, size_t ws_size,
                              hipStream_t stream) {
  const float* x    = (const float*)d_in[0];
  const float* W_ih = (const float*)d_in[1];
  const float* W_hh = (const float*)d_in[2];
  const float* b_ih = (const float*)d_in[3];
  const float* b_hh = (const float*)d_in[4];
  float* out = (float*)d_out;
  hipLaunchKernelGGL(lstm_fused, dim3(512), dim3(256), 0, stream,
                     x, W_ih, W_hh, b_ih, b_hh, out);
}

// Round 7
// 224.938 us; speedup vs baseline: 1.9004x; 1.9004x over previous
//
#include <hip/hip_runtime.h>

// LSTM: B=1024, S=512, E=H=50, fp32 in/out.
// Grid: 256 blocks x 512 threads (8 waves, 2/SIMD). Each block owns 4 chains for all 512 steps.
// Waves 0-5: 2 M-tiles each; wave 6: 1 M-tile; wave 7: x-stager. (13 tiles cover 208 gate rows.)
// gates(16x16 tiles) = W_reordered(208x128, fp16 in VGPRs) @ [x;h] (128x16, fp16 in LDS).
// Gate reorder j = h*4 + g -> lane's 4 acc regs = {i,f,g,o} for one (chain,h).
// Phase 1: h-MFMA (C-in = prefetched x-part) -> gatebuf; x-MFMA for t+1; wave7 stages x ring.
// Phase 2: threads 0-199 each update ONE real cell (full-lane trans efficiency), write h to hbuf.
// Two barriers/step; 2 waves/SIMD hide each other's latency with no duplicated work.

typedef __attribute__((ext_vector_type(8))) _Float16 f16x8;  // 8 x fp16 (4 VGPRs) MFMA operand
typedef __attribute__((ext_vector_type(4))) float f32x4;

__device__ __forceinline__ float fast_sigmoid(float z) {
  return __builtin_amdgcn_rcpf(1.0f + __expf(-z));
}
__device__ __forceinline__ float fast_tanh(float z) {
  return 1.0f - 2.0f * __builtin_amdgcn_rcpf(1.0f + __expf(2.0f * z));
}

__global__ __launch_bounds__(512, 1) void lstm_fused(
    const float* __restrict__ xg,     // (1024, 512, 50)
    const float* __restrict__ W_ih,   // (200, 50)
    const float* __restrict__ W_hh,   // (200, 50)
    const float* __restrict__ b_ih,   // (200,)
    const float* __restrict__ b_hh,   // (200,)
    float* __restrict__ out)          // (1024, 1, 50)
{
  constexpr int S = 512, E = 50, H = 50;
  const int tid  = threadIdx.x;
  const int lane = tid & 63;
  const int wv   = tid >> 6;
  const int c0   = blockIdx.x << 2;   // 4 chains per block

  // LDS: xbuf ring[4 slots][2 kt][4 chains][64B] = 2048 B @0
  //      hbuf ring[2 slots][2 kt][4 chains][64B] = 1024 B @2048
  //      gatebuf [52 h][4 chains][4 f32]         = 3328 B @3072   -> 6400 B total
  __shared__ __align__(16) unsigned char lds[6400];
  for (int i = tid; i < 6400 / 4; i += 512) reinterpret_cast<unsigned*>(lds)[i] = 0u;

  const int m  = lane & 15;   // A m-index / D col
  const int kg = lane >> 4;   // k-group of 8; D row-group
  const int tstart = 2 * wv;
  const int ntiles = (wv < 6) ? 2 : ((wv == 6) ? 1 : 0);

  // ---- W fragments: register-stationary fp16 (2 tiles/wave) ----
  f16x8 wfr[2][4];
  f32x4 bias[2];
#pragma unroll
  for (int i = 0; i < 2; ++i) {
    const int  mt    = tstart + i;
    const bool tv    = (i < ntiles);
    const int  j     = mt * 16 + m;     // reordered gate idx = h*4 + g
    const int  hh    = j >> 2, g = j & 3;
    const bool rowok = tv && (hh < H);
#pragma unroll
    for (int kt = 0; kt < 4; ++kt) {
      f16x8 s;
#pragma unroll
      for (int jj = 0; jj < 8; ++jj) {
        const int k = kt * 32 + kg * 8 + jj;
        float w = 0.0f;
        if (rowok) {
          if (k < 50)                  w = W_ih[(g * 50 + hh) * 50 + k];
          else if (k >= 64 && k < 114) w = W_hh[(g * 50 + hh) * 50 + (k - 64)];
        }
        s[jj] = (_Float16)w;
      }
      wfr[i][kt] = s;
    }
    f32x4 bv;
#pragma unroll
    for (int r = 0; r < 4; ++r) {
      const int jr = mt * 16 + kg * 4 + r;
      const int hr = jr >> 2, gr = jr & 3;
      bv[r] = (tv && hr < H) ? (b_ih[gr * 50 + hr] + b_hh[gr * 50 + hr]) : 0.0f;
    }
    bias[i] = bv;
  }

  // ---- cell-thread constants (threads 0..199: one real cell each) ----
  const bool iscell = (tid < 200);
  const int  cchain = tid & 3;
  const int  ch     = tid >> 2;       // 0..49
  float cst = 0.0f;

  // ---- wave 7: x stagers (4 (chain,e) slots per lane, statically unrolled) ----
  const bool isstg = (wv == 7);
  bool     sok[4];
  long     gb[4];
  unsigned la[4];
  float    A[4], B[4];
#pragma unroll
  for (int u = 0; u < 4; ++u) {
    const int xs = lane + 64 * u;
    sok[u] = isstg && (xs < 200);
    const int chn = sok[u] ? (xs / 50) : 0;
    const int e   = sok[u] ? (xs - 50 * chn) : 0;
    gb[u] = ((long)(c0 + chn) * S) * E + e;
    la[u] = (unsigned)(((e >> 5) << 8) + (chn << 6) + ((e & 31) << 1));
    A[u] = 0.f; B[u] = 0.f;
  }

  __syncthreads();   // zeros visible (pads + h0 = 0)

  // prime x slots 0,1; load x[2],x[3] into stage regs
#pragma unroll
  for (int u = 0; u < 4; ++u) {
    if (sok[u]) {
      *reinterpret_cast<_Float16*>(lds + 0 * 512 + la[u]) = (_Float16)xg[gb[u] + 0 * E];
      *reinterpret_cast<_Float16*>(lds + 1 * 512 + la[u]) = (_Float16)xg[gb[u] + 1 * E];
    }
  }
#pragma unroll
  for (int u = 0; u < 4; ++u) {
    if (sok[u]) { A[u] = xg[gb[u] + 2 * E]; B[u] = xg[gb[u] + 3 * E]; }
  }
  __syncthreads();   // x slots 0,1 staged

  const int      bc  = lane & 3;
  const unsigned bro = (unsigned)((bc << 6) + (kg << 4));

  // ---- prime xcur = bias + W_x @ x[0] (slot 0) ----
  f32x4 xcur[2];
  {
    const f16x8 b0 = *reinterpret_cast<const f16x8*>(lds + 0u + bro);
    const f16x8 b1 = *reinterpret_cast<const f16x8*>(lds + 256u + bro);
#pragma unroll
    for (int i = 0; i < 2; ++i) {
      f32x4 a = bias[i];
      a = __builtin_amdgcn_mfma_f32_16x16x32_f16(wfr[i][0], b0, a, 0, 0, 0);
      a = __builtin_amdgcn_mfma_f32_16x16x32_f16(wfr[i][1], b1, a, 0, 0, 0);
      xcur[i] = a;
    }
  }

  auto phase1 = [&](int t, float (&P)[4]) {
    if (ntiles > 0) {
      const unsigned hs = 2048u + (unsigned)(t & 1) * 512u;
      const unsigned xs = (unsigned)((t + 1) & 3) * 512u;
      const f16x8 b2  = *reinterpret_cast<const f16x8*>(lds + hs + bro);
      const f16x8 b3  = *reinterpret_cast<const f16x8*>(lds + hs + 256u + bro);
      const f16x8 nb0 = *reinterpret_cast<const f16x8*>(lds + xs + bro);
      const f16x8 nb1 = *reinterpret_cast<const f16x8*>(lds + xs + 256u + bro);
#pragma unroll
      for (int i = 0; i < 2; ++i) {
        f32x4 a = xcur[i];
        a = __builtin_amdgcn_mfma_f32_16x16x32_f16(wfr[i][2], b2, a, 0, 0, 0);
        a = __builtin_amdgcn_mfma_f32_16x16x32_f16(wfr[i][3], b3, a, 0, 0, 0);
        if ((m < 4) && (i < ntiles)) {
          const int h = (tstart + i) * 4 + kg;     // 0..51 (50,51 = pad rows, in-bounds)
          *reinterpret_cast<f32x4*>(lds + 3072u + (unsigned)(h * 64 + m * 16)) = a;
        }
        f32x4 c = bias[i];
        c = __builtin_amdgcn_mfma_f32_16x16x32_f16(wfr[i][0], nb0, c, 0, 0, 0);
        c = __builtin_amdgcn_mfma_f32_16x16x32_f16(wfr[i][1], nb1, c, 0, 0, 0);
        xcur[i] = c;
      }
    } else if (isstg) {
      if (t + 2 < S) {
        const unsigned sl = (unsigned)((t + 2) & 3) * 512u;
#pragma unroll
        for (int u = 0; u < 4; ++u)
          if (sok[u]) *reinterpret_cast<_Float16*>(lds + sl + la[u]) = (_Float16)P[u];
        if (t + 4 < S) {
#pragma unroll
          for (int u = 0; u < 4; ++u)
            if (sok[u]) P[u] = xg[gb[u] + (long)(t + 4) * E];
        }
      }
    }
  };

  auto phase2 = [&](int t) {
    if (iscell) {
      const f32x4 g4 = *reinterpret_cast<const f32x4*>(lds + 3072u + (unsigned)(tid * 16));
      const float ig = fast_sigmoid(g4[0]);
      const float fg = fast_sigmoid(g4[1]);
      const float gg = fast_tanh   (g4[2]);
      const float og = fast_sigmoid(g4[3]);
      const float c  = fg * cst + ig * gg;
      cst = c;
      const float hv = og * fast_tanh(c);
      if (t == S - 1) {
        out[(long)(c0 + cchain) * H + ch] = hv;
      } else {
        *reinterpret_cast<_Float16*>(
            lds + 2048u + (unsigned)((t + 1) & 1) * 512u +
            (unsigned)(((ch >> 5) << 8) + (cchain << 6) + ((ch & 31) << 1))) = (_Float16)hv;
      }
    }
  };

  for (int t = 0; t < S; t += 2) {
    phase1(t, A);
    __syncthreads();
    phase2(t);
    __syncthreads();
    phase1(t + 1, B);
    __syncthreads();
    phase2(t + 1);
    __syncthreads();
  }
}

extern "C" void kernel_launch(void* const* d_in, const int* in_sizes, int n_in,
                              void* d_out, int out_size, void* d_ws, size_t ws_size,
                              hipStream_t stream) {
  const float* x    = (const float*)d_in[0];
  const float* W_ih = (const float*)d_in[1];
  const float* W_hh = (const float*)d_in[2];
  const float* b_ih = (const float*)d_in[3];
  const float* b_hh = (const float*)d_in[4];
  float* out = (float*)d_out;
  hipLaunchKernelGGL(lstm_fused, dim3(256), dim3(512), 0, stream,
                     x, W_ih, W_hh, b_ih, b_hh, out);
}

// Round 8
// 220.609 us; speedup vs baseline: 1.9377x; 1.0196x over previous
//
#include <hip/hip_runtime.h>

// LSTM: B=1024, S=512, E=H=50, fp32 in/out.
// Grid: 256 blocks x 512 threads (8 waves, 2/SIMD). Each block owns 4 chains for all 512 steps.
// Waves 0-5: 2 M-tiles each; wave 6: 1 M-tile; wave 7: x-stager. (13 tiles cover 208 gate rows.)
// gates(16x16 tiles) = W_reordered(208x128, fp16 in VGPRs) @ [x;h] (128x16, fp16 in LDS).
// Gate reorder j = h*4 + g -> lane's 4 acc regs = {i,f,g,o} for one (chain,h).
// SINGLE barrier per step: h-MFMA -> intra-wave ds_bpermute redistributes the wave's 32 cells
// onto lanes 0-31 (no LDS gatebuf, no second barrier) -> lane-local cell update -> h ds_write.
// x-part of t+1 prefetched via xcur; wave 7 stages the x ring 2 steps ahead.

typedef __attribute__((ext_vector_type(8))) _Float16 f16x8;  // 8 x fp16 (4 VGPRs) MFMA operand
typedef __attribute__((ext_vector_type(4))) float f32x4;

__device__ __forceinline__ float fast_sigmoid(float z) {
  return __builtin_amdgcn_rcpf(1.0f + __expf(-z));
}
__device__ __forceinline__ float fast_tanh(float z) {
  return 1.0f - 2.0f * __builtin_amdgcn_rcpf(1.0f + __expf(2.0f * z));
}

__global__ __launch_bounds__(512, 1) void lstm_fused(
    const float* __restrict__ xg,     // (1024, 512, 50)
    const float* __restrict__ W_ih,   // (200, 50)
    const float* __restrict__ W_hh,   // (200, 50)
    const float* __restrict__ b_ih,   // (200,)
    const float* __restrict__ b_hh,   // (200,)
    float* __restrict__ out)          // (1024, 1, 50)
{
  constexpr int S = 512, E = 50, H = 50;
  const int tid  = threadIdx.x;
  const int lane = tid & 63;
  const int wv   = tid >> 6;
  const int c0   = blockIdx.x << 2;   // 4 chains per block

  // LDS: xbuf ring[4 slots][2 kt][4 chains][64B] = 2048 B @0
  //      hbuf ring[2 slots][2 kt][4 chains][64B] = 1024 B @2048
  __shared__ __align__(16) unsigned char lds[3072];
  for (int i = tid; i < 3072 / 4; i += 512) reinterpret_cast<unsigned*>(lds)[i] = 0u;

  const int m  = lane & 15;   // A m-index / D col
  const int kg = lane >> 4;   // k-group of 8; D row-group
  const int tstart = 2 * wv;
  const int ntiles = (wv < 6) ? 2 : ((wv == 6) ? 1 : 0);

  // ---- W fragments: register-stationary fp16 (2 tiles/wave) ----
  f16x8 wfr[2][4];
  f32x4 bias[2];
#pragma unroll
  for (int i = 0; i < 2; ++i) {
    const int  mt    = tstart + i;
    const bool tv    = (i < ntiles);
    const int  j     = mt * 16 + m;     // reordered gate idx = h*4 + g
    const int  hh    = j >> 2, g = j & 3;
    const bool rowok = tv && (hh < H);
#pragma unroll
    for (int kt = 0; kt < 4; ++kt) {
      f16x8 s;
#pragma unroll
      for (int jj = 0; jj < 8; ++jj) {
        const int k = kt * 32 + kg * 8 + jj;
        float w = 0.0f;
        if (rowok) {
          if (k < 50)                  w = W_ih[(g * 50 + hh) * 50 + k];
          else if (k >= 64 && k < 114) w = W_hh[(g * 50 + hh) * 50 + (k - 64)];
        }
        s[jj] = (_Float16)w;
      }
      wfr[i][kt] = s;
    }
    f32x4 bv;
#pragma unroll
    for (int r = 0; r < 4; ++r) {
      const int jr = mt * 16 + kg * 4 + r;
      const int hr = jr >> 2, gr = jr & 3;
      bv[r] = (tv && hr < H) ? (b_ih[gr * 50 + hr] + b_hh[gr * 50 + hr]) : 0.0f;
    }
    bias[i] = bv;
  }

  // ---- activation-lane constants: lanes 0..16*ntiles-1 each own one cell ----
  const int  al_i  = lane >> 4;               // tile select (0/1)
  const int  al_kg = (lane >> 2) & 3;
  const int  al_c  = lane & 3;                // chain
  const int  al_h  = 4 * (tstart + al_i) + al_kg;
  const bool al_ok = (lane < 16 * ntiles) && (al_h < H);
  const int  bpaddr = ((((lane >> 2) & 3) * 16 + (lane & 3)) << 2);  // src lane*4 for ds_bpermute
  const unsigned hwr = (unsigned)(((al_h >> 5) << 8) + (al_c << 6) + ((al_h & 31) << 1));
  float cst = 0.0f;

  // ---- wave 7: x stagers (4 (chain,e) slots per lane) ----
  const bool isstg = (wv == 7);
  bool     sok[4];
  long     gb[4];
  unsigned la[4];
  float    A[4], B[4];
#pragma unroll
  for (int u = 0; u < 4; ++u) {
    const int xs = lane + 64 * u;
    sok[u] = isstg && (xs < 200);
    const int chn = sok[u] ? (xs / 50) : 0;
    const int e   = sok[u] ? (xs - 50 * chn) : 0;
    gb[u] = ((long)(c0 + chn) * S) * E + e;
    la[u] = (unsigned)(((e >> 5) << 8) + (chn << 6) + ((e & 31) << 1));
    A[u] = 0.f; B[u] = 0.f;
  }

  __syncthreads();   // zeros visible (pads + h0 = 0)

  // prime x slots 0,1; load x[2],x[3] into stage regs
#pragma unroll
  for (int u = 0; u < 4; ++u) {
    if (sok[u]) {
      *reinterpret_cast<_Float16*>(lds + 0 * 512 + la[u]) = (_Float16)xg[gb[u] + 0 * E];
      *reinterpret_cast<_Float16*>(lds + 1 * 512 + la[u]) = (_Float16)xg[gb[u] + 1 * E];
    }
  }
#pragma unroll
  for (int u = 0; u < 4; ++u) {
    if (sok[u]) { A[u] = xg[gb[u] + 2 * E]; B[u] = xg[gb[u] + 3 * E]; }
  }
  __syncthreads();   // x slots 0,1 staged

  const int      bc  = lane & 3;
  const unsigned bro = (unsigned)((bc << 6) + (kg << 4));

  // ---- prime xcur = bias + W_x @ x[0] (slot 0) ----
  f32x4 xcur[2];
  {
    const f16x8 b0 = *reinterpret_cast<const f16x8*>(lds + 0u + bro);
    const f16x8 b1 = *reinterpret_cast<const f16x8*>(lds + 256u + bro);
#pragma unroll
    for (int i = 0; i < 2; ++i) {
      f32x4 a = bias[i];
      a = __builtin_amdgcn_mfma_f32_16x16x32_f16(wfr[i][0], b0, a, 0, 0, 0);
      a = __builtin_amdgcn_mfma_f32_16x16x32_f16(wfr[i][1], b1, a, 0, 0, 0);
      xcur[i] = a;
    }
  }

  auto step = [&](int t, float (&P)[4]) {
    if (ntiles > 0) {
      const unsigned hs = 2048u + (unsigned)(t & 1) * 512u;
      const unsigned xs = (unsigned)((t + 1) & 3) * 512u;
      const f16x8 b2  = *reinterpret_cast<const f16x8*>(lds + hs + bro);
      const f16x8 b3  = *reinterpret_cast<const f16x8*>(lds + hs + 256u + bro);
      const f16x8 nb0 = *reinterpret_cast<const f16x8*>(lds + xs + bro);
      const f16x8 nb1 = *reinterpret_cast<const f16x8*>(lds + xs + 256u + bro);

      // critical path: h-part, chain depth 2, C-in = precomputed x-part
      f32x4 acc0 = xcur[0];
      acc0 = __builtin_amdgcn_mfma_f32_16x16x32_f16(wfr[0][2], b2, acc0, 0, 0, 0);
      acc0 = __builtin_amdgcn_mfma_f32_16x16x32_f16(wfr[0][3], b3, acc0, 0, 0, 0);
      f32x4 acc1 = xcur[1];
      acc1 = __builtin_amdgcn_mfma_f32_16x16x32_f16(wfr[1][2], b2, acc1, 0, 0, 0);
      acc1 = __builtin_amdgcn_mfma_f32_16x16x32_f16(wfr[1][3], b3, acc1, 0, 0, 0);

      // off-critical-path: x-part for step t+1
      {
        f32x4 c0v = bias[0];
        c0v = __builtin_amdgcn_mfma_f32_16x16x32_f16(wfr[0][0], nb0, c0v, 0, 0, 0);
        c0v = __builtin_amdgcn_mfma_f32_16x16x32_f16(wfr[0][1], nb1, c0v, 0, 0, 0);
        xcur[0] = c0v;
        f32x4 c1v = bias[1];
        c1v = __builtin_amdgcn_mfma_f32_16x16x32_f16(wfr[1][0], nb0, c1v, 0, 0, 0);
        c1v = __builtin_amdgcn_mfma_f32_16x16x32_f16(wfr[1][1], nb1, c1v, 0, 0, 0);
        xcur[1] = c1v;
      }

      // intra-wave redistribute: cell (tile i, h-sub kg, chain m<4) from lane kg*16+m
      // (regs r=0..3 = gates i,f,g,o) onto lane L = i*16 + kg*4 + m.
      float gv[4];
#pragma unroll
      for (int r = 0; r < 4; ++r) {
        const int p0 = __builtin_amdgcn_ds_bpermute(bpaddr, __float_as_int(acc0[r]));
        const int p1 = __builtin_amdgcn_ds_bpermute(bpaddr, __float_as_int(acc1[r]));
        gv[r] = __int_as_float((lane < 16) ? p0 : p1);
      }

      if (al_ok) {
        const float ig = fast_sigmoid(gv[0]);
        const float fg = fast_sigmoid(gv[1]);
        const float gg = fast_tanh   (gv[2]);
        const float og = fast_sigmoid(gv[3]);
        const float c  = fg * cst + ig * gg;
        cst = c;
        const float hv = og * fast_tanh(c);
        if (t == S - 1) {
          out[(long)(c0 + al_c) * H + al_h] = hv;
        } else {
          *reinterpret_cast<_Float16*>(
              lds + 2048u + (unsigned)((t + 1) & 1) * 512u + hwr) = (_Float16)hv;
        }
      }
    } else if (isstg) {
      if (t + 2 < S) {
        const unsigned sl = (unsigned)((t + 2) & 3) * 512u;
#pragma unroll
        for (int u = 0; u < 4; ++u)
          if (sok[u]) *reinterpret_cast<_Float16*>(lds + sl + la[u]) = (_Float16)P[u];
        if (t + 4 < S) {
#pragma unroll
          for (int u = 0; u < 4; ++u)
            if (sok[u]) P[u] = xg[gb[u] + (long)(t + 4) * E];
        }
      }
    }
    __syncthreads();   // h slot (t+1)&1 and x slot (t+2)&3 complete
  };

  for (int t = 0; t < S; t += 2) {
    step(t, A);
    step(t + 1, B);
  }
}

extern "C" void kernel_launch(void* const* d_in, const int* in_sizes, int n_in,
                              void* d_out, int out_size, void* d_ws, size_t ws_size,
                              hipStream_t stream) {
  const float* x    = (const float*)d_in[0];
  const float* W_ih = (const float*)d_in[1];
  const float* W_hh = (const float*)d_in[2];
  const float* b_ih = (const float*)d_in[3];
  const float* b_hh = (const float*)d_in[4];
  float* out = (float*)d_out;
  hipLaunchKernelGGL(lstm_fused, dim3(256), dim3(512), 0, stream,
                     x, W_ih, W_hh, b_ih, b_hh, out);
}